// Round 10
// baseline (6215.996 us; speedup 1.0000x reference)
//
#include <hip/hip_runtime.h>

static constexpr int TT = 512, BBATCH = 64, DD = 256, HH = 1024, OOUT = 64;

typedef float f32x4 __attribute__((ext_vector_type(4)));
typedef short bfrag __attribute__((ext_vector_type(8)));

__device__ __forceinline__ float sigm(float x) { return 1.0f / (1.0f + __expf(-x)); }
__device__ __forceinline__ float tanh_fast(float x) {
    return 1.0f - 2.0f / (__expf(2.0f * x) + 1.0f);   // exact at clip bounds
}
// fp32 -> bf16 bits, round-to-nearest-even (finite inputs only)
__device__ __forceinline__ unsigned short f2bf(float f) {
    unsigned int u = __builtin_bit_cast(unsigned int, f);
    u += 0x7FFFu + ((u >> 16) & 1u);
    return (unsigned short)(u >> 16);
}

struct Params {
    const float *x, *W_real, *W_imag, *U_w, *U_b, *W_tau_w, *W_tau_b,
                *mask_real, *mask_imag, *tau_bias, *b_real, *b_imag, *out_w, *out_b;
    float* out;             // [T][B][O]
    unsigned short* act;    // ws: [3 mats][2 parity][B][H] bf16
    float* zread;           // ws: [2 parity][B][H] f32
    unsigned int* bar;      // ws: 4 group counters, 128B apart (memset to 0 per launch)
};

// Device-coherent load: bypass L1+L2 (serviced past L2 -> full-latency RT).
#define LDC(v_, p_, o_) asm volatile("global_load_dwordx4 %0, %1, off offset:" #o_ " sc0 sc1" \
                                     : "=v"(v_) : "v"(p_))
#define WAITV(n_) do { asm volatile("s_waitcnt vmcnt(" #n_ ")" ::: "memory"); \
                       __builtin_amdgcn_sched_barrier(0); } while (0)
#define MFMA(a_, b_, c_) __builtin_amdgcn_mfma_f32_16x16x32_bf16(a_, b_, c_, 0, 0, 0)
// Device-coherent store (write-through, no local-L2 dirty allocate).
#define STC(p_, v_) __hip_atomic_store((p_), (v_), __ATOMIC_RELAXED, __HIP_MEMORY_SCOPE_AGENT)

// ===================== PROVEN round-8 main kernel (verbatim) =====================
// 256 WGs x 512 threads, 1 WG/CU (LDS 114688B), persistent, cooperative.
// 4 b-groups of 64 WGs. Cross-WG state flows through the device-coherent path;
// wave-6 Ux(t+1) and wave-7 readout(t-1) execute inside the barrier-wait window.
__global__ void __launch_bounds__(512, 2) lnn_fused(Params p) {
    extern __shared__ char smem[];
    unsigned short* Wlds = (unsigned short*)smem;                      // [3][16][1024] bf16, swizzled
    unsigned short* Ulds = (unsigned short*)(smem + 3 * 16 * 1024 * 2);// [16][256]  bf16, swizzled
    float* EX = (float*)(smem + 3 * 16 * 1024 * 2 + 16 * 256 * 2);     // [8][256] f32 partials

    const int tid = threadIdx.x;
    const int wave = tid >> 6, lane = tid & 63;
    const int g = blockIdx.x;
    const int grp = (g & 7) >> 1;                 // b-group 0..3 (64 WGs each)
    const int slot = ((g >> 3) << 1) | (g & 1);   // h-slot 0..63 within group
    const int h0 = slot * 16, b0 = grp * 16;
    const int ro_b0 = b0 + (slot & 3) * 4, ro_o0 = (slot >> 2) * 4;

    for (int i = tid; i < 3 * 16 * 1024; i += 512) {
        const int mat = i >> 14, r = (i >> 10) & 15, k = i & 1023;
        const int idx = (h0 + r) * HH + k;
        float w;
        if (mat == 0)      w = p.W_real[idx] * sigm(p.mask_real[idx]);
        else if (mat == 1) w = p.W_imag[idx] * sigm(p.mask_imag[idx]);
        else               w = p.W_tau_w[idx];
        const int gk = (k >> 3) ^ (r & 7);
        Wlds[(mat * 16 + r) * 1024 + gk * 8 + (k & 7)] = f2bf(w);
    }
    for (int i = tid; i < 16 * 256; i += 512) {
        const int r = i >> 8, k = i & 255;
        const int gk = (k >> 3) ^ (r & 7);
        Ulds[r * 256 + gk * 8 + (k & 7)] = f2bf(p.U_w[(h0 + r) * DD + k]);
    }

    float zr = 0.f, zi = 0.f, cbr = 0.f, cbi = 0.f, cwtb = 0.f, ctb = 0.f, cub = 0.f;
    int myoff = 0;
    if (tid < 256) {
        const int myb = b0 + (tid >> 4), myh = h0 + (tid & 15);
        myoff = myb * HH + myh;
        cbr = p.b_real[myh]; cbi = p.b_imag[myh];
        cwtb = p.W_tau_b[myh]; ctb = p.tau_bias[myh]; cub = p.U_b[myh];
        STC(p.act + (0 * 2 + 1) * BBATCH * HH + myoff, (unsigned short)0);
        STC(p.act + (1 * 2 + 1) * BBATCH * HH + myoff, (unsigned short)0);
        STC(p.act + (2 * 2 + 1) * BBATCH * HH + myoff, (unsigned short)0);
    }

    unsigned int* bar = p.bar + grp * 32;  // 128B-separated counters
    auto arrive = [&]() {
        __hip_atomic_fetch_add(bar, 1u, __ATOMIC_RELAXED, __HIP_MEMORY_SCOPE_AGENT);
    };
    auto waitbar = [&](unsigned int tgt) {
        int guard = 1 << 20;
        while (__hip_atomic_load(bar, __ATOMIC_RELAXED, __HIP_MEMORY_SCOPE_AGENT) < tgt
               && --guard)
            __builtin_amdgcn_s_sleep(1);
    };

    auto uxcomp = [&](int tx) {   // wave 6: Ux(x[tx]) -> EX section 6 + (tx&1)
        const int m = lane & 15, kb = lane >> 4, sw = m & 7;
        const float* xrow = p.x + ((size_t)tx * BBATCH + (b0 + m)) * DD;
        const unsigned short* urow = Ulds + m * 256;
        f32x4 acc = {0.f, 0.f, 0.f, 0.f};
        #pragma unroll
        for (int ks = 0; ks < 8; ++ks) {
            const int k = ks * 32 + kb * 8;
            const f32x4 x0 = *(const f32x4*)(xrow + k);
            const f32x4 x1 = *(const f32x4*)(xrow + k + 4);
            bfrag a;
            a[0]=(short)f2bf(x0[0]); a[1]=(short)f2bf(x0[1]);
            a[2]=(short)f2bf(x0[2]); a[3]=(short)f2bf(x0[3]);
            a[4]=(short)f2bf(x1[0]); a[5]=(short)f2bf(x1[1]);
            a[6]=(short)f2bf(x1[2]); a[7]=(short)f2bf(x1[3]);
            const bfrag b = *(const bfrag*)(urow + (((ks * 4 + kb) ^ sw) << 3));
            acc = MFMA(a, b, acc);
        }
        float* e = EX + (6 + (tx & 1)) * 256;
        #pragma unroll
        for (int q = 0; q < 4; ++q)
            e[(kb * 4 + q) * 16 + m] = acc[q];
    };
    auto readout = [&](int ty) {  // wave 7: y[ty], 2-bank pipelined coherent reads
        const int r = lane & 15, kq = lane >> 4;
        const int bb = ro_b0 + (r >> 2), oo = ro_o0 + (r & 3);
        const float* zp = p.zread + (ty & 1) * BBATCH * HH + bb * HH + kq * 256;
        const float* owp = p.out_w + oo * HH + kq * 256;
        float acc = 0.f;
        f32x4 A0,A1,A2,A3,A4,A5,A6,A7,A8,A9,A10,A11,A12,A13,A14,A15;
        f32x4 B0,B1,B2,B3,B4,B5,B6,B7,B8,B9,B10,B11,B12,B13,B14,B15;
        #define ISSUE_BANK(P_, zq_) do { \
            LDC(P_##0,zq_,0);    LDC(P_##1,zq_,16);   LDC(P_##2,zq_,32);   LDC(P_##3,zq_,48);  \
            LDC(P_##4,zq_,64);   LDC(P_##5,zq_,80);   LDC(P_##6,zq_,96);   LDC(P_##7,zq_,112); \
            LDC(P_##8,zq_,128);  LDC(P_##9,zq_,144);  LDC(P_##10,zq_,160); LDC(P_##11,zq_,176);\
            LDC(P_##12,zq_,192); LDC(P_##13,zq_,208); LDC(P_##14,zq_,224); LDC(P_##15,zq_,240);} while (0)
        #define DOT_BANK(P_, wq_) do { const f32x4* wq = (const f32x4*)(wq_); \
            acc += P_##0[0]*wq[0][0]+P_##0[1]*wq[0][1]+P_##0[2]*wq[0][2]+P_##0[3]*wq[0][3]; \
            acc += P_##1[0]*wq[1][0]+P_##1[1]*wq[1][1]+P_##1[2]*wq[1][2]+P_##1[3]*wq[1][3]; \
            acc += P_##2[0]*wq[2][0]+P_##2[1]*wq[2][1]+P_##2[2]*wq[2][2]+P_##2[3]*wq[2][3]; \
            acc += P_##3[0]*wq[3][0]+P_##3[1]*wq[3][1]+P_##3[2]*wq[3][2]+P_##3[3]*wq[3][3]; \
            acc += P_##4[0]*wq[4][0]+P_##4[1]*wq[4][1]+P_##4[2]*wq[4][2]+P_##4[3]*wq[4][3]; \
            acc += P_##5[0]*wq[5][0]+P_##5[1]*wq[5][1]+P_##5[2]*wq[5][2]+P_##5[3]*wq[5][3]; \
            acc += P_##6[0]*wq[6][0]+P_##6[1]*wq[6][1]+P_##6[2]*wq[6][2]+P_##6[3]*wq[6][3]; \
            acc += P_##7[0]*wq[7][0]+P_##7[1]*wq[7][1]+P_##7[2]*wq[7][2]+P_##7[3]*wq[7][3]; \
            acc += P_##8[0]*wq[8][0]+P_##8[1]*wq[8][1]+P_##8[2]*wq[8][2]+P_##8[3]*wq[8][3]; \
            acc += P_##9[0]*wq[9][0]+P_##9[1]*wq[9][1]+P_##9[2]*wq[9][2]+P_##9[3]*wq[9][3]; \
            acc += P_##10[0]*wq[10][0]+P_##10[1]*wq[10][1]+P_##10[2]*wq[10][2]+P_##10[3]*wq[10][3]; \
            acc += P_##11[0]*wq[11][0]+P_##11[1]*wq[11][1]+P_##11[2]*wq[11][2]+P_##11[3]*wq[11][3]; \
            acc += P_##12[0]*wq[12][0]+P_##12[1]*wq[12][1]+P_##12[2]*wq[12][2]+P_##12[3]*wq[12][3]; \
            acc += P_##13[0]*wq[13][0]+P_##13[1]*wq[13][1]+P_##13[2]*wq[13][2]+P_##13[3]*wq[13][3]; \
            acc += P_##14[0]*wq[14][0]+P_##14[1]*wq[14][1]+P_##14[2]*wq[14][2]+P_##14[3]*wq[14][3]; \
            acc += P_##15[0]*wq[15][0]+P_##15[1]*wq[15][1]+P_##15[2]*wq[15][2]+P_##15[3]*wq[15][3]; } while (0)
        ISSUE_BANK(A, (zp));
        ISSUE_BANK(B, (zp + 64));
        WAITV(16); DOT_BANK(A, owp);
        ISSUE_BANK(A, (zp + 128));
        WAITV(16); DOT_BANK(B, owp + 64);
        ISSUE_BANK(B, (zp + 192));
        WAITV(16); DOT_BANK(A, owp + 128);
        WAITV(0);  DOT_BANK(B, owp + 192);
        #undef ISSUE_BANK
        #undef DOT_BANK
        acc += __shfl_xor(acc, 16, 64);
        acc += __shfl_xor(acc, 32, 64);
        if (kq == 0)
            p.out[(size_t)ty * BBATCH * OOUT + bb * OOUT + oo] = acc + p.out_b[oo];
    };

    __syncthreads();
    if (wave == 6) uxcomp(0);

    __syncthreads();
    if (tid == 0) { arrive(); waitbar(64u); }
    __syncthreads();

    for (int t = 0; t < TT; ++t) {
        const int rp = (t + 1) & 1;
        const int wp = t & 1;

        if (wave < 6) {
            const int mat = wave >> 1, half = wave & 1;
            const int m = lane & 15, kb = lane >> 4, sw = m & 7;
            const unsigned short* ap = p.act + (mat * 2 + rp) * BBATCH * HH
                                       + (b0 + m) * HH + half * 512 + kb * 8;
            bfrag a0,a1,a2,a3,a4,a5,a6,a7,a8,a9,a10,a11,a12,a13,a14,a15;
            LDC(a0,ap,0);    LDC(a1,ap,64);   LDC(a2,ap,128);  LDC(a3,ap,192);
            LDC(a4,ap,256);  LDC(a5,ap,320);  LDC(a6,ap,384);  LDC(a7,ap,448);
            LDC(a8,ap,512);  LDC(a9,ap,576);  LDC(a10,ap,640); LDC(a11,ap,704);
            LDC(a12,ap,768); LDC(a13,ap,832); LDC(a14,ap,896); LDC(a15,ap,960);
            f32x4 acc = {0.f, 0.f, 0.f, 0.f};
            const unsigned short* wrow = Wlds + (mat * 16 + m) * 1024;
            #define STW(ks_, av_) acc = MFMA(av_, *(const bfrag*)(wrow + \
                ((((half << 6) + ((ks_) << 2) + kb) ^ sw) << 3)), acc);
            WAITV(8);
            STW(0,a0) STW(1,a1) STW(2,a2) STW(3,a3)
            STW(4,a4) STW(5,a5) STW(6,a6) STW(7,a7)
            WAITV(0);
            STW(8,a8) STW(9,a9) STW(10,a10) STW(11,a11)
            STW(12,a12) STW(13,a13) STW(14,a14) STW(15,a15)
            #undef STW
            #pragma unroll
            for (int q = 0; q < 4; ++q)
                EX[wave * 256 + (kb * 4 + q) * 16 + m] = acc[q];
        }

        __syncthreads();

        if (tid < 256) {
            const float mr = EX[0 * 256 + tid] + EX[1 * 256 + tid];
            const float mi = EX[2 * 256 + tid] + EX[3 * 256 + tid];
            const float mt = EX[4 * 256 + tid] + EX[5 * 256 + tid];
            const float ux = EX[(6 + (t & 1)) * 256 + tid] + cub;
            const float dr0 = -zr + mr + ux + cbr;
            const float di0 = -zi + mi + ux + cbi;
            float tau = sigm(mt + cwtb) + ctb;
            tau = fminf(fmaxf(tau, 0.01f), 1.0f) + 1e-6f;
            const float dzr = fminf(fmaxf(dr0 / tau, -10.f), 10.f);
            const float dzi = fminf(fmaxf(di0 / tau, -10.f), 10.f);
            zr = fminf(fmaxf(zr + 0.1f * dzr, -100.f), 100.f);
            zi = fminf(fmaxf(zi + 0.1f * dzi, -100.f), 100.f);
            const float ar = tanh_fast(zr), ai = tanh_fast(zi);
            const float zm = sqrtf(zr * zr + zi * zi + 1e-20f);
            STC(p.act + (0 * 2 + wp) * BBATCH * HH + myoff, f2bf(ar));
            STC(p.act + (1 * 2 + wp) * BBATCH * HH + myoff, f2bf(ai));
            STC(p.act + (2 * 2 + wp) * BBATCH * HH + myoff, f2bf(zm));
            STC(p.zread + wp * BBATCH * HH + myoff, zr);
        }

        __syncthreads();
        if (tid == 0) arrive();
        if (wave == 6 && t + 1 < TT) uxcomp(t + 1);
        if (wave == 7 && t >= 1) readout(t - 1);
        if (tid == 0) waitbar(64u * (t + 2));
        __syncthreads();
    }

    if (wave == 7) readout(TT - 1);
}

// ===================== lm-mechanism diagnostic (duration-encoded) =====================
// 64 blocks x 64 thr, non-cooperative, bounded. Blocks publish XCC_ID via the PROVEN
// agent path, rank-pair with a same-XCC partner (pigeonhole: pairs exist under any
// mapping), then run `iters` ping-pong RTs using PLAIN stores + sc0 loads (the lm
// primitive), with a payload word written before each flag (store-ordering check).
// Duration verdict: works ~0.2-0.5ms; flag-broken ~1-2ms (guard burn); data-broken
// >=3ms (deliberate spin). Writes only ws scratch; deterministic up to timing.
__global__ void __launch_bounds__(64) lnn_diag(unsigned int* base, int iters) {
    if (threadIdx.x != 0) return;
    unsigned int xreg;
    asm volatile("s_getreg_b32 %0, hwreg(HW_REG_XCC_ID)" : "=s"(xreg));
    const unsigned int myx = xreg & 15u;
    const int b = blockIdx.x;
    __hip_atomic_store(base + b, myx, __ATOMIC_RELAXED, __HIP_MEMORY_SCOPE_AGENT);
    __hip_atomic_fetch_add(base + 64, 1u, __ATOMIC_RELAXED, __HIP_MEMORY_SCOPE_AGENT);
    int gd0 = 1 << 20;
    while (__hip_atomic_load(base + 64, __ATOMIC_RELAXED, __HIP_MEMORY_SCOPE_AGENT) < 64u
           && --gd0)
        __builtin_amdgcn_s_sleep(1);
    if (!gd0) return;

    unsigned int xs[64];
    for (int j = 0; j < 64; ++j) {
        unsigned int v;
        const unsigned int* q = base + j;
        asm volatile("global_load_dword %0, %1, off sc0 sc1\n\ts_waitcnt vmcnt(0)"
                     : "=v"(v) : "v"(q) : "memory");
        xs[j] = v;
    }
    int r = 0;
    for (int j = 0; j < b; ++j) if (xs[j] == myx) ++r;
    const int role = r & 1;
    int partner = -1;
    if (role == 0) { for (int j = b + 1; j < 64; ++j) if (xs[j] == myx) { partner = j; break; } }
    else           { for (int j = b - 1; j >= 0; --j) if (xs[j] == myx) { partner = j; break; } }
    if (partner < 0) return;
    const int pid = (role == 0) ? b : partner;
    unsigned int* mb = base + 128 + pid * 32;   // flag word, 128B-exclusive per pair
    unsigned int* pl = mb + 8;                  // payload word, same pair region

    unsigned int bad = 0;
    for (int i = 0; i < iters; ++i) {
        const unsigned int tgt = 2u * (unsigned)i + (unsigned)role;
        unsigned int v = 0; int gd = 1 << 14;
        for (;;) {
            asm volatile("global_load_dword %0, %1, off sc0\n\ts_waitcnt vmcnt(0)"
                         : "=v"(v) : "v"(mb) : "memory");
            if (v >= tgt) break;
            if (!--gd) break;
            __builtin_amdgcn_s_sleep(0);
        }
        if (v < tgt) { bad |= 2u; break; }      // flag propagation broken: exit (guard burned)
        if (tgt) {                               // partner wrote payload tgt*K before flag tgt
            unsigned int pv;
            asm volatile("global_load_dword %0, %1, off sc0\n\ts_waitcnt vmcnt(0)"
                         : "=v"(pv) : "v"(pl) : "memory");
            if (pv != tgt * 2654435761u) bad |= 1u;
        }
        const unsigned int nv = tgt + 1u;
        asm volatile("global_store_dword %0, %1, off" :: "v"(pl), "v"(nv * 2654435761u) : "memory");
        asm volatile("s_waitcnt vmcnt(0)" ::: "memory");
        asm volatile("global_store_dword %0, %1, off" :: "v"(mb), "v"(nv) : "memory");
        asm volatile("s_waitcnt vmcnt(0)" ::: "memory");
    }
    if (bad & 1u)                                // data incoherence: long spin (>=3ms signal)
        for (int s = 0; s < (1 << 17); ++s) __builtin_amdgcn_s_sleep(1);
}

extern "C" void kernel_launch(void* const* d_in, const int* in_sizes, int n_in,
                              void* d_out, int out_size, void* d_ws, size_t ws_size,
                              hipStream_t stream) {
    Params p;
    p.x         = (const float*)d_in[0];
    p.W_real    = (const float*)d_in[1];
    p.W_imag    = (const float*)d_in[2];
    p.U_w       = (const float*)d_in[3];
    p.U_b       = (const float*)d_in[4];
    p.W_tau_w   = (const float*)d_in[5];
    p.W_tau_b   = (const float*)d_in[6];
    p.mask_real = (const float*)d_in[7];
    p.mask_imag = (const float*)d_in[8];
    p.tau_bias  = (const float*)d_in[9];
    p.b_real    = (const float*)d_in[10];
    p.b_imag    = (const float*)d_in[11];
    p.out_w     = (const float*)d_in[12];
    p.out_b     = (const float*)d_in[13];
    p.out   = (float*)d_out;
    p.act   = (unsigned short*)d_ws;                          // 786432 B
    p.zread = (float*)((char*)d_ws + 786432);                 // 524288 B
    p.bar   = (unsigned int*)((char*)d_ws + 1310720);         // 512 B

    hipMemsetAsync((char*)d_ws + 1310720, 0, 512, stream);    // barrier counters

    constexpr unsigned smem = 3 * 16 * 1024 * 2 + 16 * 256 * 2 + 8 * 256 * 4; // 114688 B
    hipFuncSetAttribute(reinterpret_cast<const void*>(lnn_fused),
                        hipFuncAttributeMaxDynamicSharedMemorySize, smem);
    void* args[] = { &p };
    hipLaunchCooperativeKernel(reinterpret_cast<const void*>(lnn_fused),
                               dim3(256), dim3(512), args, smem, stream);

    // ---- lm diagnostic, appended after the main kernel (ws scratch only) ----
    if (ws_size >= (size_t)1376256 + 12288) {
        unsigned int* dbase = (unsigned int*)((char*)d_ws + 1376256);
        hipMemsetAsync((char*)d_ws + 1376256, 0, 12288, stream);
        hipLaunchKernelGGL(lnn_diag, dim3(64), dim3(64), 0, stream, dbase, 512);
    }
}

// Round 12
// 4866.316 us; speedup vs baseline: 1.2774x; 1.2774x over previous
//
#include <hip/hip_runtime.h>

static constexpr int TT = 512, BBATCH = 64, DD = 256, HH = 1024, OOUT = 64;

typedef float f32x4 __attribute__((ext_vector_type(4)));
typedef short bfrag __attribute__((ext_vector_type(8)));

__device__ __forceinline__ float sigm(float x) { return 1.0f / (1.0f + __expf(-x)); }
__device__ __forceinline__ float tanh_fast(float x) {
    return 1.0f - 2.0f / (__expf(2.0f * x) + 1.0f);   // exact at clip bounds
}
// fp32 -> bf16 bits, round-to-nearest-even (finite inputs only)
__device__ __forceinline__ unsigned short f2bf(float f) {
    unsigned int u = __builtin_bit_cast(unsigned int, f);
    u += 0x7FFFu + ((u >> 16) & 1u);
    return (unsigned short)(u >> 16);
}

struct Params {
    const float *x, *W_real, *W_imag, *U_w, *U_b, *W_tau_w, *W_tau_b,
                *mask_real, *mask_imag, *tau_bias, *b_real, *b_imag, *out_w, *out_b;
    float* out;             // [T][B][O]
    unsigned short* act;    // flag path: [3 mat][3 ring][B][H] bf16 ; r8 path: [3][2][B][H]
    float* zread;           // flag path: [3 ring][B][H] f32        ; r8 path: [2][B][H]
    unsigned int* bar;      // r8 path: 4 group counters / flag path: global init ctr
    unsigned int* flags;    // flag path: [4 grp][64 slot] u32, 128B stride
};

// Device-coherent load: bypass L1+L2 (serviced past L2 -> full-latency RT).
#define LDC(v_, p_, o_) asm volatile("global_load_dwordx4 %0, %1, off offset:" #o_ " sc0 sc1" \
                                     : "=v"(v_) : "v"(p_))
#define WAITV(n_) do { asm volatile("s_waitcnt vmcnt(" #n_ ")" ::: "memory"); \
                       __builtin_amdgcn_sched_barrier(0); } while (0)
#define MFMA(a_, b_, c_) __builtin_amdgcn_mfma_f32_16x16x32_bf16(a_, b_, c_, 0, 0, 0)
// Device-coherent store (write-through, no local-L2 dirty allocate).
#define STC(p_, v_) __hip_atomic_store((p_), (v_), __ATOMIC_RELAXED, __HIP_MEMORY_SCOPE_AGENT)

// ===================== flag-gate kernel (round-12 = round-11 + final gate) =====================
// 256 WGs x 512 thr, 1 WG/CU, cooperative. 4 b-groups of 64 WGs (blockIdx).
// Transport identical to proven r8 (AGENT/LLC). Sync: per-WG monotone flags +
// 64-lane vector poll; act/zread are 3-slot rings (read (t+2)%3, write t%3);
// spread<=1 => in-loop reads race-free. Round-12 fix: the post-loop
// readout(TT-1) is now gated on flags >= TT (the one unprotected read in r11).
__global__ void __launch_bounds__(512, 2) lnn_flag(Params p) {
    extern __shared__ char smem[];
    unsigned short* Wlds = (unsigned short*)smem;                      // [3][16][1024] bf16, swizzled
    unsigned short* Ulds = (unsigned short*)(smem + 3 * 16 * 1024 * 2);// [16][256]  bf16, swizzled
    float* EX = (float*)(smem + 3 * 16 * 1024 * 2 + 16 * 256 * 2);     // [8][256] f32 partials

    const int tid = threadIdx.x;
    const int wave = tid >> 6, lane = tid & 63;
    const int g = blockIdx.x;
    const int grp = (g & 7) >> 1;                 // b-group 0..3 (64 WGs each)
    const int slot = ((g >> 3) << 1) | (g & 1);   // h-slot 0..63 within group
    const int h0 = slot * 16, b0 = grp * 16;
    const int ro_b0 = b0 + (slot & 3) * 4, ro_o0 = (slot >> 2) * 4;
    const int SEC = BBATCH * HH;                  // 65536

    for (int i = tid; i < 3 * 16 * 1024; i += 512) {
        const int mat = i >> 14, r = (i >> 10) & 15, k = i & 1023;
        const int idx = (h0 + r) * HH + k;
        float w;
        if (mat == 0)      w = p.W_real[idx] * sigm(p.mask_real[idx]);
        else if (mat == 1) w = p.W_imag[idx] * sigm(p.mask_imag[idx]);
        else               w = p.W_tau_w[idx];
        const int gk = (k >> 3) ^ (r & 7);
        Wlds[(mat * 16 + r) * 1024 + gk * 8 + (k & 7)] = f2bf(w);
    }
    for (int i = tid; i < 16 * 256; i += 512) {
        const int r = i >> 8, k = i & 255;
        const int gk = (k >> 3) ^ (r & 7);
        Ulds[r * 256 + gk * 8 + (k & 7)] = f2bf(p.U_w[(h0 + r) * DD + k]);
    }

    float zr = 0.f, zi = 0.f, cbr = 0.f, cbi = 0.f, cwtb = 0.f, ctb = 0.f, cub = 0.f;
    int myoff = 0;
    if (tid < 256) {
        const int myb = b0 + (tid >> 4), myh = h0 + (tid & 15);
        myoff = myb * HH + myh;
        cbr = p.b_real[myh]; cbi = p.b_imag[myh];
        cwtb = p.W_tau_b[myh]; ctb = p.tau_bias[myh]; cub = p.U_b[myh];
        // ring slot 2 = state "t-1" of step 0: tanh(0)=0, |z0|~0
        STC(p.act + (0 * 3 + 2) * SEC + myoff, (unsigned short)0);
        STC(p.act + (1 * 3 + 2) * SEC + myoff, (unsigned short)0);
        STC(p.act + (2 * 3 + 2) * SEC + myoff, (unsigned short)0);
    }

    // ---- one global init barrier (proven AGENT pattern): init + LDS visible ----
    __syncthreads();
    if (tid == 0) {
        __hip_atomic_fetch_add(p.bar, 1u, __ATOMIC_RELAXED, __HIP_MEMORY_SCOPE_AGENT);
        int gd = 1 << 20;
        while (__hip_atomic_load(p.bar, __ATOMIC_RELAXED, __HIP_MEMORY_SCOPE_AGENT) < 256u
               && --gd)
            __builtin_amdgcn_s_sleep(1);
    }
    __syncthreads();

    unsigned int* myflag = p.flags + (grp * 64 + slot) * 32;      // 128B-exclusive
    const unsigned int* pollp = p.flags + (grp * 64 + lane) * 32; // lane j <-> slot j

    auto gate = [&](unsigned int tgt, int gd) {   // caller wave: poll all 64 group flags
        unsigned int v;
        do {
            asm volatile("global_load_dword %0, %1, off sc0 sc1\n\ts_waitcnt vmcnt(0)"
                         : "=v"(v) : "v"(pollp) : "memory");
            if (__all(v >= tgt)) break;
            __builtin_amdgcn_s_sleep(1);
        } while (--gd);
    };

    auto readout = [&](int ty) {  // wave 7: y[ty], 2-bank pipelined coherent reads
        const int r = lane & 15, kq = lane >> 4;
        const int bb = ro_b0 + (r >> 2), oo = ro_o0 + (r & 3);
        const float* zp = p.zread + (ty % 3) * SEC + bb * HH + kq * 256;
        const float* owp = p.out_w + oo * HH + kq * 256;
        float acc = 0.f;
        f32x4 A0,A1,A2,A3,A4,A5,A6,A7,A8,A9,A10,A11,A12,A13,A14,A15;
        f32x4 B0,B1,B2,B3,B4,B5,B6,B7,B8,B9,B10,B11,B12,B13,B14,B15;
        #define ISSUE_BANK(P_, zq_) do { \
            LDC(P_##0,zq_,0);    LDC(P_##1,zq_,16);   LDC(P_##2,zq_,32);   LDC(P_##3,zq_,48);  \
            LDC(P_##4,zq_,64);   LDC(P_##5,zq_,80);   LDC(P_##6,zq_,96);   LDC(P_##7,zq_,112); \
            LDC(P_##8,zq_,128);  LDC(P_##9,zq_,144);  LDC(P_##10,zq_,160); LDC(P_##11,zq_,176);\
            LDC(P_##12,zq_,192); LDC(P_##13,zq_,208); LDC(P_##14,zq_,224); LDC(P_##15,zq_,240);} while (0)
        #define DOT_BANK(P_, wq_) do { const f32x4* wq = (const f32x4*)(wq_); \
            acc += P_##0[0]*wq[0][0]+P_##0[1]*wq[0][1]+P_##0[2]*wq[0][2]+P_##0[3]*wq[0][3]; \
            acc += P_##1[0]*wq[1][0]+P_##1[1]*wq[1][1]+P_##1[2]*wq[1][2]+P_##1[3]*wq[1][3]; \
            acc += P_##2[0]*wq[2][0]+P_##2[1]*wq[2][1]+P_##2[2]*wq[2][2]+P_##2[3]*wq[2][3]; \
            acc += P_##3[0]*wq[3][0]+P_##3[1]*wq[3][1]+P_##3[2]*wq[3][2]+P_##3[3]*wq[3][3]; \
            acc += P_##4[0]*wq[4][0]+P_##4[1]*wq[4][1]+P_##4[2]*wq[4][2]+P_##4[3]*wq[4][3]; \
            acc += P_##5[0]*wq[5][0]+P_##5[1]*wq[5][1]+P_##5[2]*wq[5][2]+P_##5[3]*wq[5][3]; \
            acc += P_##6[0]*wq[6][0]+P_##6[1]*wq[6][1]+P_##6[2]*wq[6][2]+P_##6[3]*wq[6][3]; \
            acc += P_##7[0]*wq[7][0]+P_##7[1]*wq[7][1]+P_##7[2]*wq[7][2]+P_##7[3]*wq[7][3]; \
            acc += P_##8[0]*wq[8][0]+P_##8[1]*wq[8][1]+P_##8[2]*wq[8][2]+P_##8[3]*wq[8][3]; \
            acc += P_##9[0]*wq[9][0]+P_##9[1]*wq[9][1]+P_##9[2]*wq[9][2]+P_##9[3]*wq[9][3]; \
            acc += P_##10[0]*wq[10][0]+P_##10[1]*wq[10][1]+P_##10[2]*wq[10][2]+P_##10[3]*wq[10][3]; \
            acc += P_##11[0]*wq[11][0]+P_##11[1]*wq[11][1]+P_##11[2]*wq[11][2]+P_##11[3]*wq[11][3]; \
            acc += P_##12[0]*wq[12][0]+P_##12[1]*wq[12][1]+P_##12[2]*wq[12][2]+P_##12[3]*wq[12][3]; \
            acc += P_##13[0]*wq[13][0]+P_##13[1]*wq[13][1]+P_##13[2]*wq[13][2]+P_##13[3]*wq[13][3]; \
            acc += P_##14[0]*wq[14][0]+P_##14[1]*wq[14][1]+P_##14[2]*wq[14][2]+P_##14[3]*wq[14][3]; \
            acc += P_##15[0]*wq[15][0]+P_##15[1]*wq[15][1]+P_##15[2]*wq[15][2]+P_##15[3]*wq[15][3]; } while (0)
        ISSUE_BANK(A, (zp));
        ISSUE_BANK(B, (zp + 64));
        WAITV(16); DOT_BANK(A, owp);
        ISSUE_BANK(A, (zp + 128));
        WAITV(16); DOT_BANK(B, owp + 64);
        ISSUE_BANK(B, (zp + 192));
        WAITV(16); DOT_BANK(A, owp + 128);
        WAITV(0);  DOT_BANK(B, owp + 192);
        #undef ISSUE_BANK
        #undef DOT_BANK
        acc += __shfl_xor(acc, 16, 64);
        acc += __shfl_xor(acc, 32, 64);
        if (kq == 0)
            p.out[(size_t)ty * BBATCH * OOUT + bb * OOUT + oo] = acc + p.out_b[oo];
    };

    for (int t = 0; t < TT; ++t) {
        const int rr = (t + 2) % 3;   // ring slot holding state t-1
        const int wr = t % 3;         // ring slot for state t

        // gate: all group members completed step t-1 (flags >= t)
        if (wave == 0 && t > 0) gate((unsigned int)t, 1 << 14);
        __syncthreads();

        if (wave < 6) {
            const int mat = wave >> 1, half = wave & 1;
            const int m = lane & 15, kb = lane >> 4, sw = m & 7;
            const unsigned short* ap = p.act + (mat * 3 + rr) * SEC
                                       + (b0 + m) * HH + half * 512 + kb * 8;
            bfrag a0,a1,a2,a3,a4,a5,a6,a7,a8,a9,a10,a11,a12,a13,a14,a15;
            LDC(a0,ap,0);    LDC(a1,ap,64);   LDC(a2,ap,128);  LDC(a3,ap,192);
            LDC(a4,ap,256);  LDC(a5,ap,320);  LDC(a6,ap,384);  LDC(a7,ap,448);
            LDC(a8,ap,512);  LDC(a9,ap,576);  LDC(a10,ap,640); LDC(a11,ap,704);
            LDC(a12,ap,768); LDC(a13,ap,832); LDC(a14,ap,896); LDC(a15,ap,960);
            f32x4 acc = {0.f, 0.f, 0.f, 0.f};
            const unsigned short* wrow = Wlds + (mat * 16 + m) * 1024;
            #define STW(ks_, av_) acc = MFMA(av_, *(const bfrag*)(wrow + \
                ((((half << 6) + ((ks_) << 2) + kb) ^ sw) << 3)), acc);
            WAITV(8);
            STW(0,a0) STW(1,a1) STW(2,a2) STW(3,a3)
            STW(4,a4) STW(5,a5) STW(6,a6) STW(7,a7)
            WAITV(0);
            STW(8,a8) STW(9,a9) STW(10,a10) STW(11,a11)
            STW(12,a12) STW(13,a13) STW(14,a14) STW(15,a15)
            #undef STW
            #pragma unroll
            for (int q = 0; q < 4; ++q)
                EX[wave * 256 + (kb * 4 + q) * 16 + m] = acc[q];
        } else if (wave == 6) {
            // Ux(x[t]) -> EX section 6 (consumed this step, after mid-sync)
            const int m = lane & 15, kb = lane >> 4, sw = m & 7;
            const float* xrow = p.x + ((size_t)t * BBATCH + (b0 + m)) * DD;
            const unsigned short* urow = Ulds + m * 256;
            f32x4 acc = {0.f, 0.f, 0.f, 0.f};
            #pragma unroll
            for (int ks = 0; ks < 8; ++ks) {
                const int k = ks * 32 + kb * 8;
                const f32x4 x0 = *(const f32x4*)(xrow + k);
                const f32x4 x1 = *(const f32x4*)(xrow + k + 4);
                bfrag a;
                a[0]=(short)f2bf(x0[0]); a[1]=(short)f2bf(x0[1]);
                a[2]=(short)f2bf(x0[2]); a[3]=(short)f2bf(x0[3]);
                a[4]=(short)f2bf(x1[0]); a[5]=(short)f2bf(x1[1]);
                a[6]=(short)f2bf(x1[2]); a[7]=(short)f2bf(x1[3]);
                const bfrag b = *(const bfrag*)(urow + (((ks * 4 + kb) ^ sw) << 3));
                acc = MFMA(a, b, acc);
            }
            float* e = EX + 6 * 256;
            #pragma unroll
            for (int q = 0; q < 4; ++q)
                e[(kb * 4 + q) * 16 + m] = acc[q];
        } else if (t >= 1) {
            readout(t - 1);   // wave 7; gated by this step's flags>=t => state t-1 drained
        }

        __syncthreads();

        if (tid < 256) {
            const float mr = EX[0 * 256 + tid] + EX[1 * 256 + tid];
            const float mi = EX[2 * 256 + tid] + EX[3 * 256 + tid];
            const float mt = EX[4 * 256 + tid] + EX[5 * 256 + tid];
            const float ux = EX[6 * 256 + tid] + cub;
            const float dr0 = -zr + mr + ux + cbr;
            const float di0 = -zi + mi + ux + cbi;
            float tau = sigm(mt + cwtb) + ctb;
            tau = fminf(fmaxf(tau, 0.01f), 1.0f) + 1e-6f;
            const float dzr = fminf(fmaxf(dr0 / tau, -10.f), 10.f);
            const float dzi = fminf(fmaxf(di0 / tau, -10.f), 10.f);
            zr = fminf(fmaxf(zr + 0.1f * dzr, -100.f), 100.f);
            zi = fminf(fmaxf(zi + 0.1f * dzi, -100.f), 100.f);
            const float ar = tanh_fast(zr), ai = tanh_fast(zi);
            const float zm = sqrtf(zr * zr + zi * zi + 1e-20f);
            STC(p.act + (0 * 3 + wr) * SEC + myoff, f2bf(ar));
            STC(p.act + (1 * 3 + wr) * SEC + myoff, f2bf(ai));
            STC(p.act + (2 * 3 + wr) * SEC + myoff, f2bf(zm));
            STC(p.zread + wr * SEC + myoff, zr);
        }

        __syncthreads();                       // drains stores to LLC (vmcnt 0)
        if (tid == 0) STC(myflag, (unsigned int)(t + 1));   // publish step t done
    }

    // ---- round-12 fix: gate the final readout on ALL group flags >= TT ----
    if (wave == 7) {
        gate((unsigned int)TT, 1 << 16);
        readout(TT - 1);
    }
}

// ===================== PROVEN round-8 kernel (fallback, verbatim) =====================
__global__ void __launch_bounds__(512, 2) lnn_fused(Params p) {
    extern __shared__ char smem[];
    unsigned short* Wlds = (unsigned short*)smem;
    unsigned short* Ulds = (unsigned short*)(smem + 3 * 16 * 1024 * 2);
    float* EX = (float*)(smem + 3 * 16 * 1024 * 2 + 16 * 256 * 2);

    const int tid = threadIdx.x;
    const int wave = tid >> 6, lane = tid & 63;
    const int g = blockIdx.x;
    const int grp = (g & 7) >> 1;
    const int slot = ((g >> 3) << 1) | (g & 1);
    const int h0 = slot * 16, b0 = grp * 16;
    const int ro_b0 = b0 + (slot & 3) * 4, ro_o0 = (slot >> 2) * 4;

    for (int i = tid; i < 3 * 16 * 1024; i += 512) {
        const int mat = i >> 14, r = (i >> 10) & 15, k = i & 1023;
        const int idx = (h0 + r) * HH + k;
        float w;
        if (mat == 0)      w = p.W_real[idx] * sigm(p.mask_real[idx]);
        else if (mat == 1) w = p.W_imag[idx] * sigm(p.mask_imag[idx]);
        else               w = p.W_tau_w[idx];
        const int gk = (k >> 3) ^ (r & 7);
        Wlds[(mat * 16 + r) * 1024 + gk * 8 + (k & 7)] = f2bf(w);
    }
    for (int i = tid; i < 16 * 256; i += 512) {
        const int r = i >> 8, k = i & 255;
        const int gk = (k >> 3) ^ (r & 7);
        Ulds[r * 256 + gk * 8 + (k & 7)] = f2bf(p.U_w[(h0 + r) * DD + k]);
    }

    float zr = 0.f, zi = 0.f, cbr = 0.f, cbi = 0.f, cwtb = 0.f, ctb = 0.f, cub = 0.f;
    int myoff = 0;
    if (tid < 256) {
        const int myb = b0 + (tid >> 4), myh = h0 + (tid & 15);
        myoff = myb * HH + myh;
        cbr = p.b_real[myh]; cbi = p.b_imag[myh];
        cwtb = p.W_tau_b[myh]; ctb = p.tau_bias[myh]; cub = p.U_b[myh];
        STC(p.act + (0 * 2 + 1) * BBATCH * HH + myoff, (unsigned short)0);
        STC(p.act + (1 * 2 + 1) * BBATCH * HH + myoff, (unsigned short)0);
        STC(p.act + (2 * 2 + 1) * BBATCH * HH + myoff, (unsigned short)0);
    }

    unsigned int* bar = p.bar + grp * 32;
    auto arrive = [&]() {
        __hip_atomic_fetch_add(bar, 1u, __ATOMIC_RELAXED, __HIP_MEMORY_SCOPE_AGENT);
    };
    auto waitbar = [&](unsigned int tgt) {
        int guard = 1 << 20;
        while (__hip_atomic_load(bar, __ATOMIC_RELAXED, __HIP_MEMORY_SCOPE_AGENT) < tgt
               && --guard)
            __builtin_amdgcn_s_sleep(1);
    };

    auto uxcomp = [&](int tx) {
        const int m = lane & 15, kb = lane >> 4, sw = m & 7;
        const float* xrow = p.x + ((size_t)tx * BBATCH + (b0 + m)) * DD;
        const unsigned short* urow = Ulds + m * 256;
        f32x4 acc = {0.f, 0.f, 0.f, 0.f};
        #pragma unroll
        for (int ks = 0; ks < 8; ++ks) {
            const int k = ks * 32 + kb * 8;
            const f32x4 x0 = *(const f32x4*)(xrow + k);
            const f32x4 x1 = *(const f32x4*)(xrow + k + 4);
            bfrag a;
            a[0]=(short)f2bf(x0[0]); a[1]=(short)f2bf(x0[1]);
            a[2]=(short)f2bf(x0[2]); a[3]=(short)f2bf(x0[3]);
            a[4]=(short)f2bf(x1[0]); a[5]=(short)f2bf(x1[1]);
            a[6]=(short)f2bf(x1[2]); a[7]=(short)f2bf(x1[3]);
            const bfrag b = *(const bfrag*)(urow + (((ks * 4 + kb) ^ sw) << 3));
            acc = MFMA(a, b, acc);
        }
        float* e = EX + (6 + (tx & 1)) * 256;
        #pragma unroll
        for (int q = 0; q < 4; ++q)
            e[(kb * 4 + q) * 16 + m] = acc[q];
    };
    auto readout = [&](int ty) {
        const int r = lane & 15, kq = lane >> 4;
        const int bb = ro_b0 + (r >> 2), oo = ro_o0 + (r & 3);
        const float* zp = p.zread + (ty & 1) * BBATCH * HH + bb * HH + kq * 256;
        const float* owp = p.out_w + oo * HH + kq * 256;
        float acc = 0.f;
        f32x4 A0,A1,A2,A3,A4,A5,A6,A7,A8,A9,A10,A11,A12,A13,A14,A15;
        f32x4 B0,B1,B2,B3,B4,B5,B6,B7,B8,B9,B10,B11,B12,B13,B14,B15;
        #define ISSUE_BANK(P_, zq_) do { \
            LDC(P_##0,zq_,0);    LDC(P_##1,zq_,16);   LDC(P_##2,zq_,32);   LDC(P_##3,zq_,48);  \
            LDC(P_##4,zq_,64);   LDC(P_##5,zq_,80);   LDC(P_##6,zq_,96);   LDC(P_##7,zq_,112); \
            LDC(P_##8,zq_,128);  LDC(P_##9,zq_,144);  LDC(P_##10,zq_,160); LDC(P_##11,zq_,176);\
            LDC(P_##12,zq_,192); LDC(P_##13,zq_,208); LDC(P_##14,zq_,224); LDC(P_##15,zq_,240);} while (0)
        #define DOT_BANK(P_, wq_) do { const f32x4* wq = (const f32x4*)(wq_); \
            acc += P_##0[0]*wq[0][0]+P_##0[1]*wq[0][1]+P_##0[2]*wq[0][2]+P_##0[3]*wq[0][3]; \
            acc += P_##1[0]*wq[1][0]+P_##1[1]*wq[1][1]+P_##1[2]*wq[1][2]+P_##1[3]*wq[1][3]; \
            acc += P_##2[0]*wq[2][0]+P_##2[1]*wq[2][1]+P_##2[2]*wq[2][2]+P_##2[3]*wq[2][3]; \
            acc += P_##3[0]*wq[3][0]+P_##3[1]*wq[3][1]+P_##3[2]*wq[3][2]+P_##3[3]*wq[3][3]; \
            acc += P_##4[0]*wq[4][0]+P_##4[1]*wq[4][1]+P_##4[2]*wq[4][2]+P_##4[3]*wq[4][3]; \
            acc += P_##5[0]*wq[5][0]+P_##5[1]*wq[5][1]+P_##5[2]*wq[5][2]+P_##5[3]*wq[5][3]; \
            acc += P_##6[0]*wq[6][0]+P_##6[1]*wq[6][1]+P_##6[2]*wq[6][2]+P_##6[3]*wq[6][3]; \
            acc += P_##7[0]*wq[7][0]+P_##7[1]*wq[7][1]+P_##7[2]*wq[7][2]+P_##7[3]*wq[7][3]; \
            acc += P_##8[0]*wq[8][0]+P_##8[1]*wq[8][1]+P_##8[2]*wq[8][2]+P_##8[3]*wq[8][3]; \
            acc += P_##9[0]*wq[9][0]+P_##9[1]*wq[9][1]+P_##9[2]*wq[9][2]+P_##9[3]*wq[9][3]; \
            acc += P_##10[0]*wq[10][0]+P_##10[1]*wq[10][1]+P_##10[2]*wq[10][2]+P_##10[3]*wq[10][3]; \
            acc += P_##11[0]*wq[11][0]+P_##11[1]*wq[11][1]+P_##11[2]*wq[11][2]+P_##11[3]*wq[11][3]; \
            acc += P_##12[0]*wq[12][0]+P_##12[1]*wq[12][1]+P_##12[2]*wq[12][2]+P_##12[3]*wq[12][3]; \
            acc += P_##13[0]*wq[13][0]+P_##13[1]*wq[13][1]+P_##13[2]*wq[13][2]+P_##13[3]*wq[13][3]; \
            acc += P_##14[0]*wq[14][0]+P_##14[1]*wq[14][1]+P_##14[2]*wq[14][2]+P_##14[3]*wq[14][3]; \
            acc += P_##15[0]*wq[15][0]+P_##15[1]*wq[15][1]+P_##15[2]*wq[15][2]+P_##15[3]*wq[15][3]; } while (0)
        ISSUE_BANK(A, (zp));
        ISSUE_BANK(B, (zp + 64));
        WAITV(16); DOT_BANK(A, owp);
        ISSUE_BANK(A, (zp + 128));
        WAITV(16); DOT_BANK(B, owp + 64);
        ISSUE_BANK(B, (zp + 192));
        WAITV(16); DOT_BANK(A, owp + 128);
        WAITV(0);  DOT_BANK(B, owp + 192);
        #undef ISSUE_BANK
        #undef DOT_BANK
        acc += __shfl_xor(acc, 16, 64);
        acc += __shfl_xor(acc, 32, 64);
        if (kq == 0)
            p.out[(size_t)ty * BBATCH * OOUT + bb * OOUT + oo] = acc + p.out_b[oo];
    };

    __syncthreads();
    if (wave == 6) uxcomp(0);
    __syncthreads();
    if (tid == 0) { arrive(); waitbar(64u); }
    __syncthreads();

    for (int t = 0; t < TT; ++t) {
        const int rp = (t + 1) & 1;
        const int wp = t & 1;

        if (wave < 6) {
            const int mat = wave >> 1, half = wave & 1;
            const int m = lane & 15, kb = lane >> 4, sw = m & 7;
            const unsigned short* ap = p.act + (mat * 2 + rp) * BBATCH * HH
                                       + (b0 + m) * HH + half * 512 + kb * 8;
            bfrag a0,a1,a2,a3,a4,a5,a6,a7,a8,a9,a10,a11,a12,a13,a14,a15;
            LDC(a0,ap,0);    LDC(a1,ap,64);   LDC(a2,ap,128);  LDC(a3,ap,192);
            LDC(a4,ap,256);  LDC(a5,ap,320);  LDC(a6,ap,384);  LDC(a7,ap,448);
            LDC(a8,ap,512);  LDC(a9,ap,576);  LDC(a10,ap,640); LDC(a11,ap,704);
            LDC(a12,ap,768); LDC(a13,ap,832); LDC(a14,ap,896); LDC(a15,ap,960);
            f32x4 acc = {0.f, 0.f, 0.f, 0.f};
            const unsigned short* wrow = Wlds + (mat * 16 + m) * 1024;
            #define STW(ks_, av_) acc = MFMA(av_, *(const bfrag*)(wrow + \
                ((((half << 6) + ((ks_) << 2) + kb) ^ sw) << 3)), acc);
            WAITV(8);
            STW(0,a0) STW(1,a1) STW(2,a2) STW(3,a3)
            STW(4,a4) STW(5,a5) STW(6,a6) STW(7,a7)
            WAITV(0);
            STW(8,a8) STW(9,a9) STW(10,a10) STW(11,a11)
            STW(12,a12) STW(13,a13) STW(14,a14) STW(15,a15)
            #undef STW
            #pragma unroll
            for (int q = 0; q < 4; ++q)
                EX[wave * 256 + (kb * 4 + q) * 16 + m] = acc[q];
        }

        __syncthreads();

        if (tid < 256) {
            const float mr = EX[0 * 256 + tid] + EX[1 * 256 + tid];
            const float mi = EX[2 * 256 + tid] + EX[3 * 256 + tid];
            const float mt = EX[4 * 256 + tid] + EX[5 * 256 + tid];
            const float ux = EX[(6 + (t & 1)) * 256 + tid] + cub;
            const float dr0 = -zr + mr + ux + cbr;
            const float di0 = -zi + mi + ux + cbi;
            float tau = sigm(mt + cwtb) + ctb;
            tau = fminf(fmaxf(tau, 0.01f), 1.0f) + 1e-6f;
            const float dzr = fminf(fmaxf(dr0 / tau, -10.f), 10.f);
            const float dzi = fminf(fmaxf(di0 / tau, -10.f), 10.f);
            zr = fminf(fmaxf(zr + 0.1f * dzr, -100.f), 100.f);
            zi = fminf(fmaxf(zi + 0.1f * dzi, -100.f), 100.f);
            const float ar = tanh_fast(zr), ai = tanh_fast(zi);
            const float zm = sqrtf(zr * zr + zi * zi + 1e-20f);
            STC(p.act + (0 * 2 + wp) * BBATCH * HH + myoff, f2bf(ar));
            STC(p.act + (1 * 2 + wp) * BBATCH * HH + myoff, f2bf(ai));
            STC(p.act + (2 * 2 + wp) * BBATCH * HH + myoff, f2bf(zm));
            STC(p.zread + wp * BBATCH * HH + myoff, zr);
        }

        __syncthreads();
        if (tid == 0) arrive();
        if (wave == 6 && t + 1 < TT) uxcomp(t + 1);
        if (wave == 7 && t >= 1) readout(t - 1);
        if (tid == 0) waitbar(64u * (t + 2));
        __syncthreads();
    }

    if (wave == 7) readout(TT - 1);
}

extern "C" void kernel_launch(void* const* d_in, const int* in_sizes, int n_in,
                              void* d_out, int out_size, void* d_ws, size_t ws_size,
                              hipStream_t stream) {
    Params p;
    p.x         = (const float*)d_in[0];
    p.W_real    = (const float*)d_in[1];
    p.W_imag    = (const float*)d_in[2];
    p.U_w       = (const float*)d_in[3];
    p.U_b       = (const float*)d_in[4];
    p.W_tau_w   = (const float*)d_in[5];
    p.W_tau_b   = (const float*)d_in[6];
    p.mask_real = (const float*)d_in[7];
    p.mask_imag = (const float*)d_in[8];
    p.tau_bias  = (const float*)d_in[9];
    p.b_real    = (const float*)d_in[10];
    p.b_imag    = (const float*)d_in[11];
    p.out_w     = (const float*)d_in[12];
    p.out_b     = (const float*)d_in[13];
    p.out = (float*)d_out;

    constexpr unsigned smem = 3 * 16 * 1024 * 2 + 16 * 256 * 2 + 8 * 256 * 4; // 114688 B
    void* args[] = { &p };

    // flag-path layout: act 3x3 rings (1179648) | zread 3 rings (786432) |
    //                   bar (512B line) | flags 256*128B   => total 1999104 B
    constexpr size_t FL_ACT = 0, FL_Z = 1179648, FL_SYNC = 1966080;
    constexpr size_t FL_FLAGS = FL_SYNC + 128, FL_END = FL_FLAGS + 256 * 128;

    if (ws_size >= FL_END) {
        p.act   = (unsigned short*)((char*)d_ws + FL_ACT);
        p.zread = (float*)((char*)d_ws + FL_Z);
        p.bar   = (unsigned int*)((char*)d_ws + FL_SYNC);
        p.flags = (unsigned int*)((char*)d_ws + FL_FLAGS);
        hipMemsetAsync((char*)d_ws + FL_SYNC, 0, FL_END - FL_SYNC, stream);
        hipFuncSetAttribute(reinterpret_cast<const void*>(lnn_flag),
                            hipFuncAttributeMaxDynamicSharedMemorySize, smem);
        hipLaunchCooperativeKernel(reinterpret_cast<const void*>(lnn_flag),
                                   dim3(256), dim3(512), args, smem, stream);
    } else {
        // proven round-8 path
        p.act   = (unsigned short*)d_ws;                          // 786432 B
        p.zread = (float*)((char*)d_ws + 786432);                 // 524288 B
        p.bar   = (unsigned int*)((char*)d_ws + 1310720);         // 512 B
        p.flags = nullptr;
        hipMemsetAsync((char*)d_ws + 1310720, 0, 512, stream);
        hipFuncSetAttribute(reinterpret_cast<const void*>(lnn_fused),
                            hipFuncAttributeMaxDynamicSharedMemorySize, smem);
        hipLaunchCooperativeKernel(reinterpret_cast<const void*>(lnn_fused),
                                   dim3(256), dim3(512), args, smem, stream);
    }
}